// Round 3
// baseline (1137.219 us; speedup 1.0000x reference)
//
#include <hip/hip_runtime.h>
#include <hip/hip_fp16.h>

#define H_A   2048
#define H_HP  4096
#define V_A   256
#define V_HP  256
#define DEPTH 12

struct Half8 { __half2 a, b, c, d; };   // 16 B

__device__ __forceinline__ float fsig_(float x) { return 1.0f / (1.0f + __expf(-x)); }
__device__ __forceinline__ float ftanh_(float x) {
    // tanh(x) = 1 - 2/(exp(2x)+1); saturates correctly at +/-inf
    return 1.0f - 2.0f / (__expf(2.0f * x) + 1.0f);
}

__device__ __forceinline__ float dot8h_(Half8 w, float4 x0, float4 x1) {
    float2 wa = __half22float2(w.a), wb = __half22float2(w.b);
    float2 wc = __half22float2(w.c), wd = __half22float2(w.d);
    return wa.x * x0.x + wa.y * x0.y + wb.x * x0.z + wb.y * x0.w +
           wc.x * x1.x + wc.y * x1.y + wd.x * x1.z + wd.y * x1.w;
}

__device__ __forceinline__ Half8 cvt8_(float4 a, float4 b) {
    Half8 h;
    h.a = __floats2half2_rn(a.x, a.y);
    h.b = __floats2half2_rn(a.z, a.w);
    h.c = __floats2half2_rn(b.x, b.y);
    h.d = __floats2half2_rn(b.z, b.w);
    return h;
}

// Butterfly reduce: every lane ends with the full 64-lane sum.
__device__ __forceinline__ float waveReduceSum(float v) {
#pragma unroll
    for (int off = 32; off > 0; off >>= 1) v += __shfl_xor(v, off, 64);
    return v;
}

// ---------------------------------------------------------------------------
// init state (ws re-poisoned 0xAA every call -> must init every call)
// ---------------------------------------------------------------------------
__global__ void k_init(const float* __restrict__ x_a, const float* __restrict__ x_hp,
                       float* __restrict__ h_a, float* __restrict__ c_a0,
                       float* __restrict__ h_hp, float* __restrict__ c_hp,
                       float* __restrict__ a_vec, float* __restrict__ logits_hp)
{
    int i = blockIdx.x * 256 + threadIdx.x;
    if (i < H_A)  { h_a[i] = x_a[i];  c_a0[i] = 0.0f; }
    if (i < H_HP) { h_hp[i] = x_hp[i]; c_hp[i] = 0.0f; }
    if (i < V_A)  { a_vec[i] = 1.0f / 256.0f; logits_hp[i] = 0.0f; }
}

// ---------------------------------------------------------------------------
// Batched fp32->fp16 conversion of all weight matrices EXCEPT W_hh_hp
// (that one is converted by kA's idle branch-3 waves at step 0).
// Unit = 8 elements. Segment prefix sums hardcoded.
// ---------------------------------------------------------------------------
__global__ __launch_bounds__(256) void k_f2h_batched(
    const float* __restrict__ W_ih_a,  __half* __restrict__ hW_ih_a,
    const float* __restrict__ W_hh_a,  __half* __restrict__ hW_hh_a,
    const float* __restrict__ W_sum,   __half* __restrict__ hW_sum,
    const float* __restrict__ W_ih_hp, __half* __restrict__ hW_ih_hp,
    const float* __restrict__ W_out_a, __half* __restrict__ hW_out_a,
    const float* __restrict__ W_out_hp,__half* __restrict__ hW_out_hp)
{
    int i = blockIdx.x * 256 + threadIdx.x;
    const float* src; __half* dst; int base;
    if      (i < 262144)  { src = W_ih_a;   dst = hW_ih_a;   base = 0; }
    else if (i < 2359296) { src = W_hh_a;   dst = hW_hh_a;   base = 262144; }
    else if (i < 3407872) { src = W_sum;    dst = hW_sum;    base = 2359296; }
    else if (i < 4456448) { src = W_ih_hp;  dst = hW_ih_hp;  base = 3407872; }
    else if (i < 4521984) { src = W_out_a;  dst = hW_out_a;  base = 4456448; }
    else if (i < 4653056) { src = W_out_hp; dst = hW_out_hp; base = 4521984; }
    else return;
    int j = i - base;
    float4 a = ((const float4*)src)[2 * j];
    float4 b = ((const float4*)src)[2 * j + 1];
    ((Half8*)dst)[j] = cvt8_(a, b);
}

// ---------------------------------------------------------------------------
// kA: fused phase-1 GEMVs (fp16 weights, fp32 accumulate)
//   waves [0,8192):      gates_a[r]  = W_ih_a[r]·a + W_hh_a[r]·h_a + biases
//   waves [8192,10240):  h_sum[r]    = relu(W_sum[r]·h_hp + b_sum[r])
//   waves [10240,26624): gacc_hp[r]  = W_hh_hp[r]·c_hp + b_ih_hp[r] + b_hh_hp[r]
// step0: c_hp==0 exactly, so branch 3 instead CONVERTS its W_hh_hp row to fp16
// and writes the bias-only gacc.
// ---------------------------------------------------------------------------
__global__ __launch_bounds__(256) void kA_fused_gemv(
    const __half* __restrict__ hW_ih_a, const __half* __restrict__ hW_hh_a,
    const float* __restrict__ b_ih_a, const float* __restrict__ b_hh_a,
    const __half* __restrict__ hW_sum,  const float* __restrict__ b_sum,
    __half* __restrict__ hW_hh_hp, const float* __restrict__ W_hh_hp_f32,
    const float* __restrict__ b_ih_hp, const float* __restrict__ b_hh_hp,
    const float* __restrict__ a_vec,  const float* __restrict__ h_a,
    const float* __restrict__ h_hp,   const float* __restrict__ c_hp,
    float* __restrict__ gates_a, float* __restrict__ h_sum_o,
    float* __restrict__ gacc_hp, int step0)
{
    const int lane = threadIdx.x & 63;
    const int wave = (blockIdx.x << 2) | (threadIdx.x >> 6);

    if (wave < 8192) {
        const int r = wave;
        // ih: 256 cols -> 4 halves/lane (read as __half2 pair = 8B)
        const __half2* wp = (const __half2*)(hW_ih_a + (size_t)r * V_A);
        __half2 w0h = wp[2 * lane], w1h = wp[2 * lane + 1];
        float4 x = ((const float4*)a_vec)[lane];
        float2 w0 = __half22float2(w0h), w1 = __half22float2(w1h);
        float acc = w0.x * x.x + w0.y * x.y + w1.x * x.z + w1.y * x.w;
        // hh: 2048 cols -> 4 iters of 8 halves/lane
        const Half8* wh = (const Half8*)(hW_hh_a + (size_t)r * H_A);
        const float4* xh = (const float4*)h_a;
#pragma unroll
        for (int it = 0; it < 4; ++it) {
            int idx = it * 64 + lane;
            acc += dot8h_(wh[idx], xh[2 * idx], xh[2 * idx + 1]);
        }
        acc = waveReduceSum(acc);
        if (lane == 0) gates_a[r] = acc + b_ih_a[r] + b_hh_a[r];
    } else if (wave < 10240) {
        const int r = wave - 8192;
        const Half8* ww = (const Half8*)(hW_sum + (size_t)r * H_HP);
        const float4* xx = (const float4*)h_hp;
        float acc = 0.0f;
#pragma unroll
        for (int it = 0; it < 8; ++it) {
            int idx = it * 64 + lane;
            acc += dot8h_(ww[idx], xx[2 * idx], xx[2 * idx + 1]);
        }
        acc = waveReduceSum(acc);
        if (lane == 0) h_sum_o[r] = fmaxf(acc + b_sum[r], 0.0f);
    } else {
        const int r = wave - 10240;
        if (step0) {
            // convert row r of W_hh_hp (4096 floats) to fp16
            const float4* src = (const float4*)(W_hh_hp_f32 + (size_t)r * H_HP);
            Half8* dst = (Half8*)(hW_hh_hp + (size_t)r * H_HP);
#pragma unroll
            for (int it = 0; it < 8; ++it) {
                int idx = it * 64 + lane;
                dst[idx] = cvt8_(src[2 * idx], src[2 * idx + 1]);
            }
            if (lane == 0) gacc_hp[r] = b_ih_hp[r] + b_hh_hp[r];
        } else {
            const Half8* ww = (const Half8*)(hW_hh_hp + (size_t)r * H_HP);
            const float4* xx = (const float4*)c_hp;
            float acc = 0.0f;
#pragma unroll
            for (int it = 0; it < 8; ++it) {
                int idx = it * 64 + lane;
                acc += dot8h_(ww[idx], xx[2 * idx], xx[2 * idx + 1]);
            }
            acc = waveReduceSum(acc);
            if (lane == 0) gacc_hp[r] = acc + b_ih_hp[r] + b_hh_hp[r];
        }
    }
}

// ---------------------------------------------------------------------------
// kB: arch pointwise LSTM (redundant per block, h into LDS) + W_out_a GEMV
// (fp16 weights). Block 0 also writes c_out / h_a global state.
// 64 blocks x 256 threads -> 256 rows.
// ---------------------------------------------------------------------------
__global__ __launch_bounds__(256) void kB_arch(
    const float* __restrict__ gates_a, const float* __restrict__ c_in,
    float* __restrict__ c_out, float* __restrict__ h_a_g,
    const __half* __restrict__ hW_out_a, const float* __restrict__ b_out_a,
    float* __restrict__ logits_a)
{
    __shared__ float h_s[H_A];
    const int t = threadIdx.x;
#pragma unroll
    for (int k = 0; k < 8; ++k) {
        int e = t + k * 256;
        float gi = gates_a[e];
        float gf = gates_a[H_A + e];
        float gg = gates_a[2 * H_A + e];
        float go = gates_a[3 * H_A + e];
        float c_new = fsig_(gf) * c_in[e] + fsig_(gi) * ftanh_(gg);
        float h = fsig_(go) * ftanh_(c_new);
        h_s[e] = h;
        if (blockIdx.x == 0) { c_out[e] = c_new; h_a_g[e] = h; }
    }
    __syncthreads();
    const int lane = t & 63;
    const int r = (blockIdx.x << 2) | (t >> 6);
    const Half8* w8 = (const Half8*)(hW_out_a + (size_t)r * H_A);
    const float4* h4 = (const float4*)h_s;
    float acc = 0.0f;
#pragma unroll
    for (int it = 0; it < 4; ++it) {
        int idx = it * 64 + lane;
        acc += dot8h_(w8[idx], h4[2 * idx], h4[2 * idx + 1]);
    }
    acc = waveReduceSum(acc);
    if (lane == 0) logits_a[r] = acc + b_out_a[r];
}

// ---------------------------------------------------------------------------
// kC: per-block redundant double softmax (a from logits_a, a_hp from
// logits_hp of the PREVIOUS step) into LDS, then
//   gacc_hp[r] += W_ih_hp[r] · [a(256), a_hp(256)]
// 1024 blocks x 256 threads; wave handles 4 rows. Block 0 writes a_vec,
// out_a[t], out_hp[t-1] (dummy at t=0; logits_hp init 0 -> softmax = 1/256,
// exactly the reference's a_hp init).
// ---------------------------------------------------------------------------
__global__ __launch_bounds__(256) void kC_softmax_ih(
    const float* __restrict__ logits_a, const float* __restrict__ logits_hp,
    const __half* __restrict__ hW_ih_hp, float* __restrict__ gacc_hp,
    float* __restrict__ a_vec_g, float* __restrict__ out_a,
    float* __restrict__ out_hp)
{
    __shared__ float p_all[512];
    __shared__ float red[8];
    const int t = threadIdx.x, lane = t & 63, wv = t >> 6;
    float la = logits_a[t], lh = logits_hp[t];
    float ma = la, mh = lh;
#pragma unroll
    for (int off = 32; off > 0; off >>= 1) {
        ma = fmaxf(ma, __shfl_xor(ma, off, 64));
        mh = fmaxf(mh, __shfl_xor(mh, off, 64));
    }
    if (lane == 0) { red[wv] = ma; red[4 + wv] = mh; }
    __syncthreads();
    ma = fmaxf(fmaxf(red[0], red[1]), fmaxf(red[2], red[3]));
    mh = fmaxf(fmaxf(red[4], red[5]), fmaxf(red[6], red[7]));
    __syncthreads();
    float ea = __expf(la - ma), eh = __expf(lh - mh);
    float sa = waveReduceSum(ea), sh = waveReduceSum(eh);
    if (lane == 0) { red[wv] = sa; red[4 + wv] = sh; }
    __syncthreads();
    sa = red[0] + red[1] + red[2] + red[3];
    sh = red[4] + red[5] + red[6] + red[7];
    float pa = ea / sa, ph = eh / sh;
    p_all[t] = pa;
    p_all[256 + t] = ph;
    if (blockIdx.x == 0) {
        a_vec_g[t] = pa;
        out_a[t] = pa;
        out_hp[t] = ph;
    }
    __syncthreads();
    const float4* x4 = (const float4*)p_all;
    float4 xa = x4[2 * lane], xb = x4[2 * lane + 1];
    const int gw = (blockIdx.x << 2) | wv;   // 0..4095
#pragma unroll
    for (int rr = 0; rr < 4; ++rr) {
        int r = (gw << 2) | rr;              // 0..16383
        Half8 w = ((const Half8*)(hW_ih_hp + (size_t)r * (V_A + V_HP)))[lane];
        float acc = dot8h_(w, xa, xb);
        acc = waveReduceSum(acc);
        if (lane == 0) gacc_hp[r] += acc;
    }
}

// ---------------------------------------------------------------------------
// kD: hp pointwise LSTM (redundant per block into LDS; reference's swapped
// states: cell input = [h_a, h_sum]) + W_out_hp GEMV (fp16) -> logits_hp.
// Block 0 writes c_hp / h_hp global state. 64 blocks x 256 threads.
// ---------------------------------------------------------------------------
__global__ __launch_bounds__(256) void kD_hp(
    const float* __restrict__ gacc_hp, const float* __restrict__ h_a,
    const float* __restrict__ h_sum, float* __restrict__ c_hp_g,
    float* __restrict__ h_hp_g,
    const __half* __restrict__ hW_out_hp, const float* __restrict__ b_out_hp,
    float* __restrict__ logits_hp)
{
    __shared__ float h_s[H_HP];
    const int t = threadIdx.x;
#pragma unroll
    for (int k = 0; k < 16; ++k) {
        int e = t + k * 256;
        float gi = gacc_hp[e];
        float gf = gacc_hp[H_HP + e];
        float gg = gacc_hp[2 * H_HP + e];
        float go = gacc_hp[3 * H_HP + e];
        float prev = (e < H_A) ? h_a[e] : h_sum[e - H_A];
        float c = fsig_(gf) * prev + fsig_(gi) * ftanh_(gg);
        float h = fsig_(go) * ftanh_(c);
        h_s[e] = h;
        if (blockIdx.x == 0) { c_hp_g[e] = c; h_hp_g[e] = h; }
    }
    __syncthreads();
    const int lane = t & 63;
    const int r = (blockIdx.x << 2) | (t >> 6);
    const Half8* w8 = (const Half8*)(hW_out_hp + (size_t)r * H_HP);
    const float4* x4 = (const float4*)h_s;
    float acc = 0.0f;
#pragma unroll
    for (int it = 0; it < 8; ++it) {
        int idx = it * 64 + lane;
        acc += dot8h_(w8[idx], x4[2 * idx], x4[2 * idx + 1]);
    }
    acc = waveReduceSum(acc);
    if (lane == 0) logits_hp[r] = acc + b_out_hp[r];
}

// ---------------------------------------------------------------------------
// tail: softmax(logits_hp) -> out_hp[DEPTH-1]
// ---------------------------------------------------------------------------
__global__ __launch_bounds__(256) void k_softmax_tail(
    const float* __restrict__ logits_hp, float* __restrict__ outp)
{
    __shared__ float red[4];
    const int t = threadIdx.x, lane = t & 63, wv = t >> 6;
    float v = logits_hp[t];
    float m = v;
#pragma unroll
    for (int off = 32; off > 0; off >>= 1) m = fmaxf(m, __shfl_xor(m, off, 64));
    if (lane == 0) red[wv] = m;
    __syncthreads();
    m = fmaxf(fmaxf(red[0], red[1]), fmaxf(red[2], red[3]));
    __syncthreads();
    float e = __expf(v - m);
    float s = waveReduceSum(e);
    if (lane == 0) red[wv] = s;
    __syncthreads();
    s = red[0] + red[1] + red[2] + red[3];
    outp[t] = e / s;
}

// ---------------------------------------------------------------------------

extern "C" void kernel_launch(void* const* d_in, const int* in_sizes, int n_in,
                              void* d_out, int out_size, void* d_ws, size_t ws_size,
                              hipStream_t stream)
{
    const float* x_a      = (const float*)d_in[0];
    const float* x_hp     = (const float*)d_in[1];
    const float* W_ih_a   = (const float*)d_in[2];
    const float* W_hh_a   = (const float*)d_in[3];
    const float* b_ih_a   = (const float*)d_in[4];
    const float* b_hh_a   = (const float*)d_in[5];
    const float* W_out_a  = (const float*)d_in[6];
    const float* b_out_a  = (const float*)d_in[7];
    const float* W_sum    = (const float*)d_in[8];
    const float* b_sum    = (const float*)d_in[9];
    const float* W_ih_hp  = (const float*)d_in[10];
    const float* W_hh_hp  = (const float*)d_in[11];
    const float* b_ih_hp  = (const float*)d_in[12];
    const float* b_hh_hp  = (const float*)d_in[13];
    const float* W_out_hp = (const float*)d_in[14];
    const float* b_out_hp = (const float*)d_in[15];

    float* out = (float*)d_out;

    // --- ws layout: fp16 weights first (16B aligned), then fp32 state ---
    __half* hW_ih_a   = (__half*)d_ws;                      //  2,097,152 halves
    __half* hW_hh_a   = hW_ih_a   + 2097152;                // 16,777,216
    __half* hW_sum    = hW_hh_a   + 16777216;               //  8,388,608
    __half* hW_ih_hp  = hW_sum    + 8388608;                //  8,388,608
    __half* hW_hh_hp  = hW_ih_hp  + 8388608;                // 67,108,864
    __half* hW_out_a  = hW_hh_hp  + 67108864;               //    524,288
    __half* hW_out_hp = hW_out_a  + 524288;                 //  1,048,576
    float* ws = (float*)(hW_out_hp + 1048576);              // fp32 state

    float* gates_a   = ws;           // 8192
    float* h_sum     = ws + 8192;    // 2048
    float* gacc_hp   = ws + 10240;   // 16384
    float* h_a       = ws + 26624;   // 2048
    float* c_a0      = ws + 28672;   // 2048
    float* c_a1      = ws + 30720;   // 2048
    float* h_hp      = ws + 32768;   // 4096
    float* c_hp      = ws + 36864;   // 4096
    float* logits_a  = ws + 40960;   // 256
    float* logits_hp = ws + 41216;   // 256
    float* a_vec     = ws + 41472;   // 256
    float* dummy     = ws + 41728;   // 256 (step-0 a_hp out slot, discarded)
    float* c_a[2]    = { c_a0, c_a1 };

    k_init<<<16, 256, 0, stream>>>(x_a, x_hp, h_a, c_a0, h_hp, c_hp, a_vec, logits_hp);

    // one batched conversion for everything except W_hh_hp (done in kA step 0)
    k_f2h_batched<<<18176, 256, 0, stream>>>(
        W_ih_a, hW_ih_a, W_hh_a, hW_hh_a, W_sum, hW_sum,
        W_ih_hp, hW_ih_hp, W_out_a, hW_out_a, W_out_hp, hW_out_hp);

    for (int t = 0; t < DEPTH; ++t) {
        kA_fused_gemv<<<6656, 256, 0, stream>>>(
            hW_ih_a, hW_hh_a, b_ih_a, b_hh_a, hW_sum, b_sum,
            hW_hh_hp, W_hh_hp, b_ih_hp, b_hh_hp,
            a_vec, h_a, h_hp, c_hp,
            gates_a, h_sum, gacc_hp, (t == 0) ? 1 : 0);

        kB_arch<<<64, 256, 0, stream>>>(gates_a, c_a[t & 1], c_a[(t + 1) & 1], h_a,
                                        hW_out_a, b_out_a, logits_a);

        kC_softmax_ih<<<1024, 256, 0, stream>>>(
            logits_a, logits_hp, hW_ih_hp, gacc_hp,
            a_vec, out + (size_t)t * V_A,
            (t == 0) ? dummy : out + (size_t)DEPTH * V_A + (size_t)(t - 1) * V_HP);

        kD_hp<<<64, 256, 0, stream>>>(gacc_hp, h_a, h_sum, c_hp, h_hp,
                                      hW_out_hp, b_out_hp, logits_hp);
    }

    k_softmax_tail<<<1, 256, 0, stream>>>(
        logits_hp, out + (size_t)DEPTH * V_A + (size_t)(DEPTH - 1) * V_HP);
}